// Round 1
// baseline (693.051 us; speedup 1.0000x reference)
//
#include <hip/hip_runtime.h>
#include <hip/hip_bf16.h>

typedef __bf16 bf16_t;
typedef __bf16 bf16x8 __attribute__((ext_vector_type(8)));
typedef float  f32x4  __attribute__((ext_vector_type(4)));
typedef int    i32x4  __attribute__((ext_vector_type(4)));

#define M_DIM 4096
#define N_DIM 12288
#define K_DIM 3072
#define NBLK  96      // K_DIM / 32 quant blocks per output row
#define BM 128
#define BN 128
#define BK 64
#define THREADS 256

// Fused dequant (Q8_0: w = scale * int8) + bf16 MFMA GEMM.
// C[t][o] = sum_k x[t][k] * (scale[o][k/32]*q[o][k]) + bias[o]
// Both A (x) and B (w) are K-major -> identical fragment read pattern
// (gemm_bt structure, verified m90-m93).
__global__ __launch_bounds__(THREADS) void dq_gemm_kernel(
    const float* __restrict__ x, const int* __restrict__ wq,
    const float* __restrict__ scales, const float* __restrict__ bias,
    float* __restrict__ out)
{
    // T2 XOR swizzle on both tiles: linear [128][64]bf16 is a 16-way
    // bank conflict on ds_read_b128 (lanes 0-15 read 16 rows, stride 128B).
    __shared__ bf16_t sA[BM * BK];
    __shared__ bf16_t sB[BN * BK];

    const int tid  = threadIdx.x;
    const int bm   = blockIdx.x / (N_DIM / BN);
    const int bn   = blockIdx.x % (N_DIM / BN);
    const int row0 = bm * BM;
    const int col0 = bn * BN;

    const int lane = tid & 63;
    const int wid  = tid >> 6;          // 4 waves, 2x2 over the 128x128 tile
    const int wr   = (wid >> 1) * 64;   // wave row offset
    const int wc   = (wid & 1) * 64;    // wave col offset
    const int fr   = lane & 15;         // fragment row/col within 16
    const int fk   = (lane >> 4) << 3;  // fragment k offset (8 elems)

    f32x4 acc[4][4];
#pragma unroll
    for (int m = 0; m < 4; ++m)
#pragma unroll
        for (int n = 0; n < 4; ++n) acc[m][n] = (f32x4)0.f;

    for (int kt = 0; kt < K_DIM / BK; ++kt) {
        const int kb = kt * BK;

        // ---- stage A: 128x64 fp32 -> bf16, 8 elems/thread/chunk ----
#pragma unroll
        for (int c = 0; c < 4; ++c) {
            int i  = c * THREADS + tid;   // 0..1023 chunks of 8
            int r  = i >> 3;              // 0..127
            int k0 = (i & 7) << 3;        // 0..56
            const float* gp = x + (size_t)(row0 + r) * K_DIM + kb + k0;
            f32x4 f0 = *(const f32x4*)gp;
            f32x4 f1 = *(const f32x4*)(gp + 4);
            bf16x8 v;
            v[0] = (bf16_t)f0[0]; v[1] = (bf16_t)f0[1];
            v[2] = (bf16_t)f0[2]; v[3] = (bf16_t)f0[3];
            v[4] = (bf16_t)f1[0]; v[5] = (bf16_t)f1[1];
            v[6] = (bf16_t)f1[2]; v[7] = (bf16_t)f1[3];
            *(bf16x8*)&sA[r * BK + (k0 ^ ((r & 7) << 3))] = v;
        }

        // ---- stage B: 128x64 int32 quants -> dequant -> bf16 ----
#pragma unroll
        for (int c = 0; c < 4; ++c) {
            int i  = c * THREADS + tid;
            int r  = i >> 3;
            int k0 = (i & 7) << 3;
            int o  = col0 + r;
            const int* gq = wq + (size_t)o * K_DIM + kb + k0;
            i32x4 q0 = *(const i32x4*)gq;
            i32x4 q1 = *(const i32x4*)(gq + 4);
            // 8 elems span k0..k0+7, all inside one 32-wide quant block
            float s = scales[o * NBLK + ((kb + k0) >> 5)];
            bf16x8 v;
            v[0] = (bf16_t)((float)q0[0] * s); v[1] = (bf16_t)((float)q0[1] * s);
            v[2] = (bf16_t)((float)q0[2] * s); v[3] = (bf16_t)((float)q0[3] * s);
            v[4] = (bf16_t)((float)q1[0] * s); v[5] = (bf16_t)((float)q1[1] * s);
            v[6] = (bf16_t)((float)q1[2] * s); v[7] = (bf16_t)((float)q1[3] * s);
            *(bf16x8*)&sB[r * BK + (k0 ^ ((r & 7) << 3))] = v;
        }

        __syncthreads();

        // ---- compute: 2 k-slices x 4x4 MFMA 16x16x32 ----
#pragma unroll
        for (int ks = 0; ks < 2; ++ks) {
            bf16x8 af[4], bg[4];
#pragma unroll
            for (int m = 0; m < 4; ++m) {
                int r = wr + m * 16 + fr;
                af[m] = *(const bf16x8*)&sA[r * BK + ((ks * 32 + fk) ^ ((r & 7) << 3))];
            }
#pragma unroll
            for (int n = 0; n < 4; ++n) {
                int r = wc + n * 16 + fr;
                bg[n] = *(const bf16x8*)&sB[r * BK + ((ks * 32 + fk) ^ ((r & 7) << 3))];
            }
#pragma unroll
            for (int m = 0; m < 4; ++m)
#pragma unroll
                for (int n = 0; n < 4; ++n)
                    acc[m][n] = __builtin_amdgcn_mfma_f32_16x16x32_bf16(
                        af[m], bg[n], acc[m][n], 0, 0, 0);
        }

        __syncthreads();
    }

    // ---- epilogue: C/D layout col=lane&15, row=(lane>>4)*4+j (m89) ----
    const int crow = (lane >> 4) << 2;
    const int ccol = lane & 15;
#pragma unroll
    for (int m = 0; m < 4; ++m) {
#pragma unroll
        for (int n = 0; n < 4; ++n) {
            int col = col0 + wc + n * 16 + ccol;
            float b = bias[col];
#pragma unroll
            for (int j = 0; j < 4; ++j) {
                int row = row0 + wr + m * 16 + crow + j;
                out[(size_t)row * N_DIM + col] = acc[m][n][j] + b;
            }
        }
    }
}

extern "C" void kernel_launch(void* const* d_in, const int* in_sizes, int n_in,
                              void* d_out, int out_size, void* d_ws, size_t ws_size,
                              hipStream_t stream) {
    const float* x      = (const float*)d_in[0];
    const int*   wq     = (const int*)d_in[1];
    const float* scales = (const float*)d_in[2];
    const float* bias   = (const float*)d_in[3];
    float*       out    = (float*)d_out;

    dim3 grid((M_DIM / BM) * (N_DIM / BN));
    dim3 block(THREADS);
    dq_gemm_kernel<<<grid, block, 0, stream>>>(x, wq, scales, bias, out);
}

// Round 2
// 477.647 us; speedup vs baseline: 1.4510x; 1.4510x over previous
//
#include <hip/hip_runtime.h>
#include <hip/hip_bf16.h>

typedef __bf16 bf16_t;
typedef __bf16 bf16x8 __attribute__((ext_vector_type(8)));
typedef float  f32x4  __attribute__((ext_vector_type(4)));
typedef int    i32x4  __attribute__((ext_vector_type(4)));

#define M_DIM 4096
#define N_DIM 12288
#define K_DIM 3072
#define NBLK  96      // K_DIM / 32 quant blocks per output row
#define BM 128
#define BN 128
#define BK 64
#define THREADS 256

// ws layout: W_bf16 [N][K] at 0 (75.5 MB), X_bf16 [M][K] after (25.2 MB)
#define W_BYTES ((size_t)N_DIM * K_DIM * 2)
#define X_BYTES ((size_t)M_DIM * K_DIM * 2)

__device__ __forceinline__ void gload_lds16(const void* g, void* l) {
    // async global->LDS, 16B/lane; LDS dest = wave-uniform base + lane*16
    __builtin_amdgcn_global_load_lds(
        (const __attribute__((address_space(1))) unsigned int*)g,
        (__attribute__((address_space(3))) unsigned int*)l, 16, 0, 0);
}

// ---------------- Pass 1a: dequant Q8_0 weights -> bf16 ----------------
// One 8-elem chunk per thread. chunks = N*K/8 = 4718592
__global__ __launch_bounds__(256) void dequant_w_kernel(
    const int* __restrict__ wq, const float* __restrict__ scales,
    bf16_t* __restrict__ W)
{
    unsigned c = blockIdx.x * 256u + threadIdx.x;   // chunk id
    unsigned o  = c / 384u;                         // 384 chunks per row
    unsigned kc = c - o * 384u;                     // chunk within row
    float s = scales[o * NBLK + (kc >> 2)];         // 4 chunks per 32-block
    const int* gq = wq + (size_t)c * 8;
    i32x4 q0 = *(const i32x4*)gq;
    i32x4 q1 = *(const i32x4*)(gq + 4);
    bf16x8 v;
    v[0] = (bf16_t)((float)q0[0] * s); v[1] = (bf16_t)((float)q0[1] * s);
    v[2] = (bf16_t)((float)q0[2] * s); v[3] = (bf16_t)((float)q0[3] * s);
    v[4] = (bf16_t)((float)q1[0] * s); v[5] = (bf16_t)((float)q1[1] * s);
    v[6] = (bf16_t)((float)q1[2] * s); v[7] = (bf16_t)((float)q1[3] * s);
    *(bf16x8*)&W[(size_t)c * 8] = v;
}

// ---------------- Pass 1b: x fp32 -> bf16 ----------------
// chunks = M*K/8 = 1572864
__global__ __launch_bounds__(256) void cvt_x_kernel(
    const float* __restrict__ x, bf16_t* __restrict__ X)
{
    unsigned c = blockIdx.x * 256u + threadIdx.x;
    const float* gp = x + (size_t)c * 8;
    f32x4 f0 = *(const f32x4*)gp;
    f32x4 f1 = *(const f32x4*)(gp + 4);
    bf16x8 v;
    v[0] = (bf16_t)f0[0]; v[1] = (bf16_t)f0[1];
    v[2] = (bf16_t)f0[2]; v[3] = (bf16_t)f0[3];
    v[4] = (bf16_t)f1[0]; v[5] = (bf16_t)f1[1];
    v[6] = (bf16_t)f1[2]; v[7] = (bf16_t)f1[3];
    *(bf16x8*)&X[(size_t)c * 8] = v;
}

// ---------------- Pass 2: m97-structure bf16 GEMM (B^T input) ----------------
// C[t][o] = sum_k X[t][k] * W[o][k] + bias[o]
__global__ __launch_bounds__(THREADS) void gemm_bt_kernel(
    const bf16_t* __restrict__ A, const bf16_t* __restrict__ B,
    const float* __restrict__ bias, float* __restrict__ out)
{
    // LINEAR LDS layout — required by global_load_lds (base + lane*16).
    __shared__ bf16_t sA[BM * BK];
    __shared__ bf16_t sB[BN * BK];

    const int tid  = threadIdx.x;
    const int bm   = blockIdx.x / (N_DIM / BN);
    const int bn   = blockIdx.x % (N_DIM / BN);
    const int row0 = bm * BM;
    const int col0 = bn * BN;

    const int lane = tid & 63;
    const int wid  = tid >> 6;
    const int wr   = (wid >> 1) * 64;
    const int wc   = (wid & 1) * 64;
    const int fr   = lane & 15;
    const int fk   = (lane >> 4) << 3;

    f32x4 acc[4][4];
#pragma unroll
    for (int m = 0; m < 4; ++m)
#pragma unroll
        for (int n = 0; n < 4; ++n) acc[m][n] = (f32x4)0.f;

    for (int kt = 0; kt < K_DIM / BK; ++kt) {
        const int kb = kt * BK;

        // stage A+B via async direct-to-LDS: 4 issues each, 16B/lane.
        // chunk i = c*256+tid covers LDS elems [i*8, i*8+8) = row i>>3, k (i&7)*8
#pragma unroll
        for (int c = 0; c < 4; ++c) {
            int i  = c * THREADS + tid;
            int wb = c * THREADS + (tid & ~63);   // wave-uniform LDS chunk base
            int r  = i >> 3;
            int k0 = (i & 7) << 3;
            gload_lds16(A + (size_t)(row0 + r) * K_DIM + kb + k0, &sA[wb * 8]);
            gload_lds16(B + (size_t)(col0 + r) * K_DIM + kb + k0, &sB[wb * 8]);
        }

        __syncthreads();

#pragma unroll
        for (int ks = 0; ks < 2; ++ks) {
            bf16x8 af[4], bg[4];
#pragma unroll
            for (int m = 0; m < 4; ++m)
                af[m] = *(const bf16x8*)&sA[(wr + m * 16 + fr) * BK + ks * 32 + fk];
#pragma unroll
            for (int n = 0; n < 4; ++n)
                bg[n] = *(const bf16x8*)&sB[(wc + n * 16 + fr) * BK + ks * 32 + fk];
#pragma unroll
            for (int m = 0; m < 4; ++m)
#pragma unroll
                for (int n = 0; n < 4; ++n)
                    acc[m][n] = __builtin_amdgcn_mfma_f32_16x16x32_bf16(
                        af[m], bg[n], acc[m][n], 0, 0, 0);
        }

        __syncthreads();
    }

    const int crow = (lane >> 4) << 2;
    const int ccol = lane & 15;
#pragma unroll
    for (int m = 0; m < 4; ++m) {
#pragma unroll
        for (int n = 0; n < 4; ++n) {
            int col = col0 + wc + n * 16 + ccol;
            float b = bias[col];
#pragma unroll
            for (int j = 0; j < 4; ++j) {
                int row = row0 + wr + m * 16 + crow + j;
                out[(size_t)row * N_DIM + col] = acc[m][n][j] + b;
            }
        }
    }
}

// ---------------- Fallback: round-1 fused kernel (if ws too small) ----------------
__global__ __launch_bounds__(THREADS) void dq_gemm_fused_kernel(
    const float* __restrict__ x, const int* __restrict__ wq,
    const float* __restrict__ scales, const float* __restrict__ bias,
    float* __restrict__ out)
{
    __shared__ bf16_t sA[BM * BK];
    __shared__ bf16_t sB[BN * BK];

    const int tid  = threadIdx.x;
    const int bm   = blockIdx.x / (N_DIM / BN);
    const int bn   = blockIdx.x % (N_DIM / BN);
    const int row0 = bm * BM;
    const int col0 = bn * BN;
    const int lane = tid & 63;
    const int wid  = tid >> 6;
    const int wr   = (wid >> 1) * 64;
    const int wc   = (wid & 1) * 64;
    const int fr   = lane & 15;
    const int fk   = (lane >> 4) << 3;

    f32x4 acc[4][4];
#pragma unroll
    for (int m = 0; m < 4; ++m)
#pragma unroll
        for (int n = 0; n < 4; ++n) acc[m][n] = (f32x4)0.f;

    for (int kt = 0; kt < K_DIM / BK; ++kt) {
        const int kb = kt * BK;
#pragma unroll
        for (int c = 0; c < 4; ++c) {
            int i  = c * THREADS + tid;
            int r  = i >> 3;
            int k0 = (i & 7) << 3;
            const float* gp = x + (size_t)(row0 + r) * K_DIM + kb + k0;
            f32x4 f0 = *(const f32x4*)gp;
            f32x4 f1 = *(const f32x4*)(gp + 4);
            bf16x8 v;
            v[0] = (bf16_t)f0[0]; v[1] = (bf16_t)f0[1];
            v[2] = (bf16_t)f0[2]; v[3] = (bf16_t)f0[3];
            v[4] = (bf16_t)f1[0]; v[5] = (bf16_t)f1[1];
            v[6] = (bf16_t)f1[2]; v[7] = (bf16_t)f1[3];
            *(bf16x8*)&sA[r * BK + (k0 ^ ((r & 7) << 3))] = v;
        }
#pragma unroll
        for (int c = 0; c < 4; ++c) {
            int i  = c * THREADS + tid;
            int r  = i >> 3;
            int k0 = (i & 7) << 3;
            int o  = col0 + r;
            const int* gq = wq + (size_t)o * K_DIM + kb + k0;
            i32x4 q0 = *(const i32x4*)gq;
            i32x4 q1 = *(const i32x4*)(gq + 4);
            float s = scales[o * NBLK + ((kb + k0) >> 5)];
            bf16x8 v;
            v[0] = (bf16_t)((float)q0[0] * s); v[1] = (bf16_t)((float)q0[1] * s);
            v[2] = (bf16_t)((float)q0[2] * s); v[3] = (bf16_t)((float)q0[3] * s);
            v[4] = (bf16_t)((float)q1[0] * s); v[5] = (bf16_t)((float)q1[1] * s);
            v[6] = (bf16_t)((float)q1[2] * s); v[7] = (bf16_t)((float)q1[3] * s);
            *(bf16x8*)&sB[r * BK + (k0 ^ ((r & 7) << 3))] = v;
        }
        __syncthreads();
#pragma unroll
        for (int ks = 0; ks < 2; ++ks) {
            bf16x8 af[4], bg[4];
#pragma unroll
            for (int m = 0; m < 4; ++m) {
                int r = wr + m * 16 + fr;
                af[m] = *(const bf16x8*)&sA[r * BK + ((ks * 32 + fk) ^ ((r & 7) << 3))];
            }
#pragma unroll
            for (int n = 0; n < 4; ++n) {
                int r = wc + n * 16 + fr;
                bg[n] = *(const bf16x8*)&sB[r * BK + ((ks * 32 + fk) ^ ((r & 7) << 3))];
            }
#pragma unroll
            for (int m = 0; m < 4; ++m)
#pragma unroll
                for (int n = 0; n < 4; ++n)
                    acc[m][n] = __builtin_amdgcn_mfma_f32_16x16x32_bf16(
                        af[m], bg[n], acc[m][n], 0, 0, 0);
        }
        __syncthreads();
    }

    const int crow = (lane >> 4) << 2;
    const int ccol = lane & 15;
#pragma unroll
    for (int m = 0; m < 4; ++m) {
#pragma unroll
        for (int n = 0; n < 4; ++n) {
            int col = col0 + wc + n * 16 + ccol;
            float b = bias[col];
#pragma unroll
            for (int j = 0; j < 4; ++j) {
                int row = row0 + wr + m * 16 + crow + j;
                out[(size_t)row * N_DIM + col] = acc[m][n][j] + b;
            }
        }
    }
}

extern "C" void kernel_launch(void* const* d_in, const int* in_sizes, int n_in,
                              void* d_out, int out_size, void* d_ws, size_t ws_size,
                              hipStream_t stream) {
    const float* x      = (const float*)d_in[0];
    const int*   wq     = (const int*)d_in[1];
    const float* scales = (const float*)d_in[2];
    const float* bias   = (const float*)d_in[3];
    float*       out    = (float*)d_out;

    if (ws_size >= W_BYTES + X_BYTES) {
        bf16_t* W = (bf16_t*)d_ws;
        bf16_t* X = (bf16_t*)((char*)d_ws + W_BYTES);
        dequant_w_kernel<<<dim3(N_DIM * K_DIM / 8 / 256), dim3(256), 0, stream>>>(wq, scales, W);
        cvt_x_kernel<<<dim3(M_DIM * K_DIM / 8 / 256), dim3(256), 0, stream>>>(x, X);
        gemm_bt_kernel<<<dim3((M_DIM / BM) * (N_DIM / BN)), dim3(THREADS), 0, stream>>>(X, W, bias, out);
    } else {
        dq_gemm_fused_kernel<<<dim3((M_DIM / BM) * (N_DIM / BN)), dim3(THREADS), 0, stream>>>(
            x, wq, scales, bias, out);
    }
}

// Round 3
// 365.106 us; speedup vs baseline: 1.8982x; 1.3082x over previous
//
#include <hip/hip_runtime.h>
#include <hip/hip_bf16.h>

typedef __bf16 bf16_t;
typedef __bf16 bf16x8 __attribute__((ext_vector_type(8)));
typedef float  f32x4  __attribute__((ext_vector_type(4)));
typedef int    i32x4  __attribute__((ext_vector_type(4)));

#define M_DIM 4096
#define N_DIM 12288
#define K_DIM 3072
#define NBLK  96      // K_DIM / 32 quant blocks per output row

// 256x256 8-phase-style GEMM geometry
#define BM 256
#define BN 256
#define BK 64
#define THREADS 512
#define NT (K_DIM / BK)   // 48 K-tiles

// ws layout: W_bf16 [N][K] at 0 (75.5 MB), X_bf16 [M][K] after (25.2 MB)
#define W_BYTES ((size_t)N_DIM * K_DIM * 2)
#define X_BYTES ((size_t)M_DIM * K_DIM * 2)

__device__ __forceinline__ void gload_lds16(const void* g, void* l) {
    // async global->LDS, 16B/lane; LDS dest = wave-uniform base + lane*16
    __builtin_amdgcn_global_load_lds(
        (const __attribute__((address_space(1))) unsigned int*)g,
        (__attribute__((address_space(3))) unsigned int*)l, 16, 0, 0);
}

// ---------------- Pass 1a: dequant Q8_0 weights -> bf16 ----------------
__global__ __launch_bounds__(256) void dequant_w_kernel(
    const int* __restrict__ wq, const float* __restrict__ scales,
    bf16_t* __restrict__ W)
{
    unsigned c = blockIdx.x * 256u + threadIdx.x;   // 8-elem chunk id
    unsigned o  = c / 384u;                         // 384 chunks per row
    unsigned kc = c - o * 384u;
    float s = scales[o * NBLK + (kc >> 2)];
    const int* gq = wq + (size_t)c * 8;
    i32x4 q0 = *(const i32x4*)gq;
    i32x4 q1 = *(const i32x4*)(gq + 4);
    bf16x8 v;
    v[0] = (bf16_t)((float)q0[0] * s); v[1] = (bf16_t)((float)q0[1] * s);
    v[2] = (bf16_t)((float)q0[2] * s); v[3] = (bf16_t)((float)q0[3] * s);
    v[4] = (bf16_t)((float)q1[0] * s); v[5] = (bf16_t)((float)q1[1] * s);
    v[6] = (bf16_t)((float)q1[2] * s); v[7] = (bf16_t)((float)q1[3] * s);
    *(bf16x8*)&W[(size_t)c * 8] = v;
}

// ---------------- Pass 1b: x fp32 -> bf16 ----------------
__global__ __launch_bounds__(256) void cvt_x_kernel(
    const float* __restrict__ x, bf16_t* __restrict__ X)
{
    unsigned c = blockIdx.x * 256u + threadIdx.x;
    const float* gp = x + (size_t)c * 8;
    f32x4 f0 = *(const f32x4*)gp;
    f32x4 f1 = *(const f32x4*)(gp + 4);
    bf16x8 v;
    v[0] = (bf16_t)f0[0]; v[1] = (bf16_t)f0[1];
    v[2] = (bf16_t)f0[2]; v[3] = (bf16_t)f0[3];
    v[4] = (bf16_t)f1[0]; v[5] = (bf16_t)f1[1];
    v[6] = (bf16_t)f1[2]; v[7] = (bf16_t)f1[3];
    *(bf16x8*)&X[(size_t)c * 8] = v;
}

// ---------------- Pass 2: 256^2 counted-vmcnt pipelined bf16 GEMM ----------------
// C[t][o] = sum_k X[t][k] * W[o][k] + bias[o]
// Swizzle (both-sides, rule #21): linear LDS chunk (row, c8) holds global
// chunk (row, c8 ^ (row&7)); achieved by pre-swizzling the per-lane GLOBAL
// source address (gload_lds writes linearly), and XOR-ing on ds_read.
__global__ __launch_bounds__(THREADS, 2) void gemm256_kernel(
    const bf16_t* __restrict__ A, const bf16_t* __restrict__ B,
    const float* __restrict__ bias, float* __restrict__ out)
{
    __shared__ bf16_t sA[2][BM * BK];   // 2 x 32 KB
    __shared__ bf16_t sB[2][BN * BK];   // 2 x 32 KB  -> 128 KB total

    const int tid  = threadIdx.x;
    const int bm   = blockIdx.x / (N_DIM / BN);
    const int bn   = blockIdx.x % (N_DIM / BN);
    const int row0 = bm * BM;
    const int col0 = bn * BN;

    const int lane = tid & 63;
    const int wid  = tid >> 6;          // 8 waves: 2 (M) x 4 (N)
    const int wr   = (wid >> 2) * 128;  // wave row offset in tile
    const int wc   = (wid & 3) * 64;    // wave col offset in tile
    const int fr   = lane & 15;         // fragment row within 16

    // swizzled ds_read column offsets (elements) for k-slice 0/1
    int cs[2];
#pragma unroll
    for (int ks = 0; ks < 2; ++ks)
        cs[ks] = ((ks * 4 + (lane >> 4)) ^ (fr & 7)) * 8;

    // staging: thread owns chunk i = j*512 + tid (j=0..3) per operand
    //   row = i>>3 = (tid>>3) + j*64 ; c8 = tid&7 ; pre-swizzled c8g = c8 ^ (row&7)
    const int rws   = tid >> 3;                       // 0..63
    const int c8g   = (tid & 7) ^ (rws & 7);
    const size_t offA = (size_t)(row0 + rws) * K_DIM + c8g * 8;
    const size_t offB = (size_t)(col0 + rws) * K_DIM + c8g * 8;
    const int ldsChunkBase = (wid * 64) * 8;          // elems; +j*512*8 per issue

    f32x4 acc[8][4];
#pragma unroll
    for (int m = 0; m < 8; ++m)
#pragma unroll
        for (int n = 0; n < 4; ++n) acc[m][n] = (f32x4)0.f;

    // ---- prologue: stage tile 0 into buf 0 ----
#pragma unroll
    for (int j = 0; j < 4; ++j) {
        gload_lds16(A + offA + (size_t)j * 64 * K_DIM, &sA[0][ldsChunkBase + j * 4096]);
        gload_lds16(B + offB + (size_t)j * 64 * K_DIM, &sB[0][ldsChunkBase + j * 4096]);
    }

    for (int t = 0; t < NT; ++t) {
        const int cur = t & 1;
        const int nxt = cur ^ 1;
        const int tn  = (t + 1 < NT) ? (t + 1) : 0;   // stray refetch on last iter: benign

        // ---- issue 8 stage loads for tile t+1 into buf[nxt] ----
        const bf16_t* Asrc = A + offA + (size_t)tn * BK;
        const bf16_t* Bsrc = B + offB + (size_t)tn * BK;
#pragma unroll
        for (int j = 0; j < 4; ++j) {
            gload_lds16(Asrc + (size_t)j * 64 * K_DIM, &sA[nxt][ldsChunkBase + j * 4096]);
            gload_lds16(Bsrc + (size_t)j * 64 * K_DIM, &sB[nxt][ldsChunkBase + j * 4096]);
        }

        // drain tile t's 8 loads; keep tile t+1's 8 in flight (T4: never vmcnt 0)
        asm volatile("s_waitcnt vmcnt(8)" ::: "memory");
        asm volatile("s_barrier" ::: "memory");   // tile t visible to all waves

        // ---- 4 quadrant phases: (mh 0/1) x (nh 0/1), 16 MFMA each ----
#pragma unroll
        for (int mh = 0; mh < 2; ++mh) {
            bf16x8 af[4][2];
#pragma unroll
            for (int m = 0; m < 4; ++m) {
                const int row = wr + mh * 64 + m * 16 + fr;
#pragma unroll
                for (int ks = 0; ks < 2; ++ks)
                    af[m][ks] = *(const bf16x8*)&sA[cur][row * BK + cs[ks]];
            }
#pragma unroll
            for (int nh = 0; nh < 2; ++nh) {
                bf16x8 bg[2][2];
#pragma unroll
                for (int n = 0; n < 2; ++n) {
                    const int row = wc + nh * 32 + n * 16 + fr;
#pragma unroll
                    for (int ks = 0; ks < 2; ++ks)
                        bg[n][ks] = *(const bf16x8*)&sB[cur][row * BK + cs[ks]];
                }
                __builtin_amdgcn_s_setprio(1);
#pragma unroll
                for (int m = 0; m < 4; ++m)
#pragma unroll
                    for (int n = 0; n < 2; ++n)
#pragma unroll
                        for (int ks = 0; ks < 2; ++ks)
                            acc[mh * 4 + m][nh * 2 + n] =
                                __builtin_amdgcn_mfma_f32_16x16x32_bf16(
                                    af[m][ks], bg[n][ks],
                                    acc[mh * 4 + m][nh * 2 + n], 0, 0, 0);
                __builtin_amdgcn_s_setprio(0);
            }
        }

        // all reads of buf[cur] done before next iter's issues overwrite it
        asm volatile("s_barrier" ::: "memory");
    }

    // ---- epilogue: C/D layout col=lane&15, row=(lane>>4)*4+j ----
    const int crow = (lane >> 4) << 2;
    const int ccol = lane & 15;
#pragma unroll
    for (int m = 0; m < 8; ++m) {
#pragma unroll
        for (int n = 0; n < 4; ++n) {
            int col = col0 + wc + n * 16 + ccol;
            float b = bias[col];
#pragma unroll
            for (int j = 0; j < 4; ++j) {
                int row = row0 + wr + m * 16 + crow + j;
                out[(size_t)row * N_DIM + col] = acc[m][n][j] + b;
            }
        }
    }
}

// ---------------- Fallback: fused kernel (if ws too small) ----------------
#define FBM 128
#define FBN 128
#define FTHREADS 256
__global__ __launch_bounds__(FTHREADS) void dq_gemm_fused_kernel(
    const float* __restrict__ x, const int* __restrict__ wq,
    const float* __restrict__ scales, const float* __restrict__ bias,
    float* __restrict__ out)
{
    __shared__ bf16_t fA[FBM * BK];
    __shared__ bf16_t fB[FBN * BK];

    const int tid  = threadIdx.x;
    const int bm   = blockIdx.x / (N_DIM / FBN);
    const int bn   = blockIdx.x % (N_DIM / FBN);
    const int row0 = bm * FBM;
    const int col0 = bn * FBN;
    const int lane = tid & 63;
    const int wid  = tid >> 6;
    const int wr   = (wid >> 1) * 64;
    const int wc   = (wid & 1) * 64;
    const int fr   = lane & 15;
    const int fk   = (lane >> 4) << 3;

    f32x4 acc[4][4];
#pragma unroll
    for (int m = 0; m < 4; ++m)
#pragma unroll
        for (int n = 0; n < 4; ++n) acc[m][n] = (f32x4)0.f;

    for (int kt = 0; kt < K_DIM / BK; ++kt) {
        const int kb = kt * BK;
#pragma unroll
        for (int c = 0; c < 4; ++c) {
            int i  = c * FTHREADS + tid;
            int r  = i >> 3;
            int k0 = (i & 7) << 3;
            const float* gp = x + (size_t)(row0 + r) * K_DIM + kb + k0;
            f32x4 f0 = *(const f32x4*)gp;
            f32x4 f1 = *(const f32x4*)(gp + 4);
            bf16x8 v;
            v[0] = (bf16_t)f0[0]; v[1] = (bf16_t)f0[1];
            v[2] = (bf16_t)f0[2]; v[3] = (bf16_t)f0[3];
            v[4] = (bf16_t)f1[0]; v[5] = (bf16_t)f1[1];
            v[6] = (bf16_t)f1[2]; v[7] = (bf16_t)f1[3];
            *(bf16x8*)&fA[r * BK + (k0 ^ ((r & 7) << 3))] = v;
        }
#pragma unroll
        for (int c = 0; c < 4; ++c) {
            int i  = c * FTHREADS + tid;
            int r  = i >> 3;
            int k0 = (i & 7) << 3;
            int o  = col0 + r;
            const int* gq = wq + (size_t)o * K_DIM + kb + k0;
            i32x4 q0 = *(const i32x4*)gq;
            i32x4 q1 = *(const i32x4*)(gq + 4);
            float s = scales[o * NBLK + ((kb + k0) >> 5)];
            bf16x8 v;
            v[0] = (bf16_t)((float)q0[0] * s); v[1] = (bf16_t)((float)q0[1] * s);
            v[2] = (bf16_t)((float)q0[2] * s); v[3] = (bf16_t)((float)q0[3] * s);
            v[4] = (bf16_t)((float)q1[0] * s); v[5] = (bf16_t)((float)q1[1] * s);
            v[6] = (bf16_t)((float)q1[2] * s); v[7] = (bf16_t)((float)q1[3] * s);
            *(bf16x8*)&fB[r * BK + (k0 ^ ((r & 7) << 3))] = v;
        }
        __syncthreads();
#pragma unroll
        for (int ks = 0; ks < 2; ++ks) {
            bf16x8 af[4], bg[4];
#pragma unroll
            for (int m = 0; m < 4; ++m) {
                int r = wr + m * 16 + fr;
                af[m] = *(const bf16x8*)&fA[r * BK + ((ks * 32 + fk) ^ ((r & 7) << 3))];
            }
#pragma unroll
            for (int n = 0; n < 4; ++n) {
                int r = wc + n * 16 + fr;
                bg[n] = *(const bf16x8*)&fB[r * BK + ((ks * 32 + fk) ^ ((r & 7) << 3))];
            }
#pragma unroll
            for (int m = 0; m < 4; ++m)
#pragma unroll
                for (int n = 0; n < 4; ++n)
                    acc[m][n] = __builtin_amdgcn_mfma_f32_16x16x32_bf16(
                        af[m], bg[n], acc[m][n], 0, 0, 0);
        }
        __syncthreads();
    }

    const int crow = (lane >> 4) << 2;
    const int ccol = lane & 15;
#pragma unroll
    for (int m = 0; m < 4; ++m) {
#pragma unroll
        for (int n = 0; n < 4; ++n) {
            int col = col0 + wc + n * 16 + ccol;
            float b = bias[col];
#pragma unroll
            for (int j = 0; j < 4; ++j) {
                int row = row0 + wr + m * 16 + crow + j;
                out[(size_t)row * N_DIM + col] = acc[m][n][j] + b;
            }
        }
    }
}

extern "C" void kernel_launch(void* const* d_in, const int* in_sizes, int n_in,
                              void* d_out, int out_size, void* d_ws, size_t ws_size,
                              hipStream_t stream) {
    const float* x      = (const float*)d_in[0];
    const int*   wq     = (const int*)d_in[1];
    const float* scales = (const float*)d_in[2];
    const float* bias   = (const float*)d_in[3];
    float*       out    = (float*)d_out;

    if (ws_size >= W_BYTES + X_BYTES) {
        bf16_t* W = (bf16_t*)d_ws;
        bf16_t* X = (bf16_t*)((char*)d_ws + W_BYTES);
        dequant_w_kernel<<<dim3(N_DIM * K_DIM / 8 / 256), dim3(256), 0, stream>>>(wq, scales, W);
        cvt_x_kernel<<<dim3(M_DIM * K_DIM / 8 / 256), dim3(256), 0, stream>>>(x, X);
        gemm256_kernel<<<dim3((M_DIM / BM) * (N_DIM / BN)), dim3(THREADS), 0, stream>>>(X, W, bias, out);
    } else {
        dq_gemm_fused_kernel<<<dim3((M_DIM / FBM) * (N_DIM / FBN)), dim3(FTHREADS), 0, stream>>>(
            x, wq, scales, bias, out);
    }
}